// Round 10
// baseline (563.999 us; speedup 1.0000x reference)
//
#include <hip/hip_runtime.h>

// FSMN depthwise strided FIR — R10: 8-wave block, intra-block TLP.
// B=32, T=2000, D=512, L=R=20, stride 2.
//
// R9 post-mortem: spill fixed (VGPR 256, FETCH 69MB, WRITE 138MB) but
// 145us > R7's 125us. Occupancy ~10% => the 2-blocks/CU co-residency
// never materialized (LDS granularity / dispatcher — uncontrollable),
// and the 9-barrier 4-step cadence cost ~15% vs R7's 4-barrier 8-step.
// R10: build the TLP INSIDE the block where residency is guaranteed:
// 8 waves (512 thr) = 2 waves/EU hiding each other's ds_read/DMA stalls
// between barriers. R7's proven 8-step/4-barrier cadence.
//
// Geometry: block = 8 waves (mg=0..7) x M_=4 m = 32 m, one d-half, one
// batch. x rows br=0..143 (x row R0+br, R0=64mb-40), 1KB each.
//   x ring: 128 rows (slot br&127), chunks of 16 rows, c=0..8.
//   filt ring: 24 rows (slot fr%24), chunks of 8 rows, c=0..5 (fr<=40).
// Phase p (0..4) = steps t=8p..8p+7 (phase 4: ..40). Per-step t the block
// touches x br in [2t, 2t+65] => phase p reads x chunks p..p+4 and filt
// rows 8p..8p+9 (chunks p,p+1).
//   Stage at phase-p start (p<=3): x chunk p+5 -> ring group (p+5)&7,
//   disjoint from read groups p..p+4; overwrites chunk p-3 (last read
//   phase p-3, 3 barriers ago). filt chunk p+2 -> slots 8*((p+2)%3)+mg,
//   overwrites rows last read <= phase p-1 (verified per-chunk: c3@p1
//   hits f-rows 0..7 read only phase 0; c4@p2 hits 8..15 read phase 1;
//   c5@p3 hits slot16 (row 40) whose old row 16 was last read phase 2).
//   DMA drained by the end-of-phase barrier; first read one phase later.
// Prologue: x chunks 0..4 (80 rows, 10/wave) + filt chunks 0,1 (2/wave).
// Tail: t=40 register-only (no pushes).
// LDS = 24 + 128 rows = 152 KB -> 1 block/CU (intended; TLP is internal).
//
// Step semantics (refcheck'd R4..R9): t<=20: ae+=f*wE, ao+=f*wO; t>=21
// swapped. E push br=8mg+2t+8; O push +1 (t<20) / -1 (t>20); O holds
// at t=20.
//
// Spill ledger: R2 no-unroll(64); R3 cap170(84); R4 cap256 clean(128);
// R7/R9 cap512 clean(256); R8 cap128 SPILL. R10: lb(512,2) cap 256 —
// the allocation this body already chose cleanly twice. 2 waves/EU x
// 256 = 512-reg/EU pool exactly.

#define B_ 32
#define T_ 2000
#define D_ 512
#define S_ 1000   // T/2
#define M_ 4      // m-positions per thread (=> 8 output rows)

#define FRING 24                  // filt ring rows
#define FOFF 0                    // filt ring base (floats)
#define XOFF (FRING * 256)        // x ring base (floats)
#define LDS_FLOATS (XOFF + 128 * 256)   // 152 KiB total

__device__ __forceinline__ float4 zf4() {
    float4 z; z.x = 0.f; z.y = 0.f; z.z = 0.f; z.w = 0.f; return z;
}

__device__ __forceinline__ void fma4(float4& a, const float4 f, const float4 w) {
    a.x = fmaf(f.x, w.x, a.x);
    a.y = fmaf(f.y, w.y, a.y);
    a.z = fmaf(f.z, w.z, a.z);
    a.w = fmaf(f.w, w.w, a.w);
}

// Async global->LDS DMA: 16B/lane x 64 lanes = one 1KB row per call.
__device__ __forceinline__ void gload_lds16(const float* g, float* l) {
    __builtin_amdgcn_global_load_lds(
        (const __attribute__((address_space(1))) void*)g,
        (__attribute__((address_space(3))) void*)l,
        16, 0, 0);
}

template<bool CHK>
__device__ __forceinline__ void fsmn_body(float* __restrict__ lds,
                                          const float* __restrict__ xb,
                                          const float* __restrict__ fb,
                                          float* __restrict__ ob,
                                          int m0, int R0, int lane, int mg)
{
    // ---- staging helpers (wave-uniform row index) ----
    auto stageX = [&](int br) {
        float* l = lds + XOFF + ((br & 127) << 8);
        const int xr = R0 + br;
        if (!CHK || (unsigned)xr < (unsigned)T_) {
            gload_lds16(xb + (size_t)xr * D_, l);     // xb already + lane*4
        } else {
            *(float4*)(l + lane * 4) = zf4();         // zero-fill pad rows
        }
    };
    // filt chunk c (rows 8c..8c+7), this wave stages row 8c+mg.
    auto stageF = [&](int c) {
        const int fr = 8 * c + mg;
        if (fr <= 40)                                 // filt has 41 rows
            gload_lds16(fb + (size_t)fr * D_,
                        lds + FOFF + ((8 * (c % 3) + mg) << 8));
    };
    // ---- LDS read helpers ----
    auto ldrow = [&](int br) -> float4 {              // x ring
        return *(const float4*)(lds + XOFF + ((br & 127) << 8) + lane * 4);
    };
    auto ldsF = [&](int t) -> float4 {                // filt ring (t compile-time)
        return *(const float4*)(lds + FOFF + ((t % FRING) << 8) + lane * 4);
    };

    // ---- Prologue: filt chunks 0,1 (rows 0..15) + x chunks 0..4 (rows 0..79) ----
    stageF(0); stageF(1);
#pragma unroll
    for (int k = 0; k < 10; ++k) stageX(8 * k + mg);
    __syncthreads();                                  // all prologue DMA done

    // ---- Init windows (rows br = 8mg..8mg+7 <= 63) + filter queue ----
    float4 wE[M_], wO[M_], ae[M_], ao[M_];
#pragma unroll
    for (int m = 0; m < M_; ++m) {
        wE[m] = ldrow(8 * mg + 2 * m);
        wO[m] = ldrow(8 * mg + 2 * m + 1);
        ae[m] = zf4(); ao[m] = zf4();
    }
    float4 qF0 = ldsF(0), qF1 = ldsF(1);              // dist-2 LDS queue

    // ---- One step (tap filt[t]); t compile-time under unroll ----
    auto dostep = [&](int t) {
        const float4 fv = qF0;
        qF0 = qF1;
        qF1 = (t + 2 <= 40) ? ldsF(t + 2) : zf4();
        if (t <= 20) {
#pragma unroll
            for (int m = 0; m < M_; ++m) { fma4(ae[m], fv, wE[m]); fma4(ao[m], fv, wO[m]); }
        } else {
#pragma unroll
            for (int m = 0; m < M_; ++m) { fma4(ao[m], fv, wE[m]); fma4(ae[m], fv, wO[m]); }
        }
        if (t < 40) {
#pragma unroll
            for (int m = 0; m < M_ - 1; ++m) wE[m] = wE[m + 1];
            wE[M_ - 1] = ldrow(8 * mg + 2 * t + 8);
            if (t != 20) {                            // O holds at junction
#pragma unroll
                for (int m = 0; m < M_ - 1; ++m) wO[m] = wO[m + 1];
                wO[M_ - 1] = ldrow(8 * mg + 2 * t + 8 + ((t < 20) ? 1 : -1));
            }
        }
    };

    // ---- Phases p=0..4 (8 steps; phase 4 has 9 incl. reg-only t=40) ----
#pragma unroll
    for (int p = 0; p < 5; ++p) {
        if (p <= 3) {                                 // stage one phase ahead
            stageX(16 * (p + 5) + 2 * mg);            // x chunk p+5 (2 rows/wave)
            stageX(16 * (p + 5) + 2 * mg + 1);
            stageF(p + 2);                            // filt chunk p+2 (1 row/wave)
        }
#pragma unroll
        for (int t = 8 * p; t < ((p == 4) ? 41 : 8 * p + 8); ++t) dostep(t);
        if (p < 4) __syncthreads();                   // drain DMA + fence reuse
    }

    // ---- Store 2*M_ output rows (coalesced float4 across 64 lanes) ----
#pragma unroll
    for (int m = 0; m < M_; ++m) {
        if (!CHK || (m0 + m) < S_) {
            *(float4*)(ob + (size_t)(2 * (m0 + m))     * D_) = ae[m];
            *(float4*)(ob + (size_t)(2 * (m0 + m) + 1) * D_) = ao[m];
        }
    }
}

__global__ __launch_bounds__(512, 2) void fsmn_kernel(
    const float* __restrict__ x, const float* __restrict__ filt,
    float* __restrict__ out)
{
    __shared__ float lds[LDS_FLOATS];      // 152 KiB: filt ring 24KB + x ring 128KB

    const int lane = threadIdx.x;          // 0..63
    const int mg   = threadIdx.y;          // 0..7 : m-group (one wave each)

    // XCD-chunked swizzle: 2048 blocks = 8 XCDs x 256 (exactly bijective).
    const int bid  = blockIdx.x;
    const int xcd  = bid & 7;
    const int slot = bid >> 3;
    const int n    = xcd * 256 + slot;     // linear id, mb-fastest
    const int mb   = n & 31;               // 0..31 : m-block (32 m each)
    const int rest = n >> 5;
    const int dh   = rest & 1;             // d-half
    const int b    = rest >> 1;            // batch

    const int m0b = mb * 32;
    const int m0  = m0b + mg * M_;
    const int d   = (dh * 64 + lane) * 4;
    const float* xb = x + (size_t)b * T_ * D_ + d;
    const float* fb = filt + d;
    float*       ob = out + (size_t)b * T_ * D_ + d;
    const int R0  = 2 * m0b - 40;          // x row of block-row 0

    // Interior iff staged rows br=0..143 all valid and all stores valid:
    // R0 >= 0 -> mb >= 1;  R0+143 <= 1999 -> mb <= 29.
    // No early-return — all 512 threads reach every barrier.
    if (mb >= 1 && mb <= 29) fsmn_body<false>(lds, xb, fb, ob, m0, R0, lane, mg);
    else                     fsmn_body<true >(lds, xb, fb, ob, m0, R0, lane, mg);
}

extern "C" void kernel_launch(void* const* d_in, const int* in_sizes, int n_in,
                              void* d_out, int out_size, void* d_ws, size_t ws_size,
                              hipStream_t stream) {
    const float* x    = (const float*)d_in[0];
    const float* filt = (const float*)d_in[1];
    float*       out  = (float*)d_out;

    dim3 block(64, 8, 1);
    // 32 m-blocks (32 m each) x 2 d-halves x 32 batches = 2048 blocks.
    dim3 grid(2048, 1, 1);
    hipLaunchKernelGGL(fsmn_kernel, grid, block, 0, stream, x, filt, out);
}

// Round 11
// 555.800 us; speedup vs baseline: 1.0148x; 1.0148x over previous
//
#include <hip/hip_runtime.h>

// FSMN depthwise strided FIR — R11: R10's 8-wave block + lb(512,1).
// B=32, T=2000, D=512, L=R=20, stride 2.
//
// R10 post-mortem: VGPR pinned at 128 + 470/698MB scratch = spill. The
// empirical launch_bounds rule on this toolchain (fit across R3/R4/R5/
// R7/R8/R9/R10): second arg w -> VGPR cap = 256/w, INDEPENDENT of block
// size. lb(512,2) meant cap 128, not the 256 I intended. The 8-wave
// intra-block-TLP hypothesis was never tested — only the cap broke it.
// R11 = R10 with lb(512,1) (cap 256, the body's natural allocation).
// A/B: vs R10 isolates the cap; vs R9 isolates intra-block TLP.
//
// Geometry (unchanged from R10, verified absmax 0.125):
// block = 8 waves (mg=0..7) x M_=4 m = 32 m, one d-half, one batch.
// x rows br=0..143 (x row R0+br, R0=64mb-40), 1KB each.
//   x ring: 128 rows (slot br&127), chunks of 16 rows, c=0..8.
//   filt ring: 24 rows (slot fr%24), chunks of 8 rows, c=0..5 (fr<=40).
// Phase p (0..4) = steps t=8p..8p+7 (phase 4: ..40); reads x chunks
// p..p+4, filt chunks p,p+1. Stage at phase-p start (p<=3): x chunk p+5
// (group (p+5)&7 disjoint from reads; overwrites chunk p-3, last read
// 3 barriers ago), filt chunk p+2 (group (p+2)%3 vs reads p%3,(p+1)%3).
// DMA drained by end-of-phase barrier; first read one phase later.
// Prologue: x chunks 0..4 (10 rows/wave) + filt chunks 0,1. Tail: t=40
// register-only. LDS = 24+128 rows = 152 KB -> 1 block/CU, TLP internal.
//
// Step semantics (refcheck'd R4..R10): t<=20: ae+=f*wE, ao+=f*wO; t>=21
// swapped. E push br=8mg+2t+8; O push +1 (t<20) / -1 (t>20); O holds
// at t=20.
//
// Spill ledger (empirical cap = 256/w): lb(256,1)->256 clean x3;
// lb(256,2)->128 (R4 clean, R8 SPILL); lb(256,3)->~85 SPILL;
// lb(512,2)->128 SPILL. R11: lb(512,1) -> cap 256.

#define B_ 32
#define T_ 2000
#define D_ 512
#define S_ 1000   // T/2
#define M_ 4      // m-positions per thread (=> 8 output rows)

#define FRING 24                  // filt ring rows
#define FOFF 0                    // filt ring base (floats)
#define XOFF (FRING * 256)        // x ring base (floats)
#define LDS_FLOATS (XOFF + 128 * 256)   // 152 KiB total

__device__ __forceinline__ float4 zf4() {
    float4 z; z.x = 0.f; z.y = 0.f; z.z = 0.f; z.w = 0.f; return z;
}

__device__ __forceinline__ void fma4(float4& a, const float4 f, const float4 w) {
    a.x = fmaf(f.x, w.x, a.x);
    a.y = fmaf(f.y, w.y, a.y);
    a.z = fmaf(f.z, w.z, a.z);
    a.w = fmaf(f.w, w.w, a.w);
}

// Async global->LDS DMA: 16B/lane x 64 lanes = one 1KB row per call.
__device__ __forceinline__ void gload_lds16(const float* g, float* l) {
    __builtin_amdgcn_global_load_lds(
        (const __attribute__((address_space(1))) void*)g,
        (__attribute__((address_space(3))) void*)l,
        16, 0, 0);
}

template<bool CHK>
__device__ __forceinline__ void fsmn_body(float* __restrict__ lds,
                                          const float* __restrict__ xb,
                                          const float* __restrict__ fb,
                                          float* __restrict__ ob,
                                          int m0, int R0, int lane, int mg)
{
    // ---- staging helpers (wave-uniform row index) ----
    auto stageX = [&](int br) {
        float* l = lds + XOFF + ((br & 127) << 8);
        const int xr = R0 + br;
        if (!CHK || (unsigned)xr < (unsigned)T_) {
            gload_lds16(xb + (size_t)xr * D_, l);     // xb already + lane*4
        } else {
            *(float4*)(l + lane * 4) = zf4();         // zero-fill pad rows
        }
    };
    // filt chunk c (rows 8c..8c+7), this wave stages row 8c+mg.
    auto stageF = [&](int c) {
        const int fr = 8 * c + mg;
        if (fr <= 40)                                 // filt has 41 rows
            gload_lds16(fb + (size_t)fr * D_,
                        lds + FOFF + ((8 * (c % 3) + mg) << 8));
    };
    // ---- LDS read helpers ----
    auto ldrow = [&](int br) -> float4 {              // x ring
        return *(const float4*)(lds + XOFF + ((br & 127) << 8) + lane * 4);
    };
    auto ldsF = [&](int t) -> float4 {                // filt ring (t compile-time)
        return *(const float4*)(lds + FOFF + ((t % FRING) << 8) + lane * 4);
    };

    // ---- Prologue: filt chunks 0,1 (rows 0..15) + x chunks 0..4 (rows 0..79) ----
    stageF(0); stageF(1);
#pragma unroll
    for (int k = 0; k < 10; ++k) stageX(8 * k + mg);
    __syncthreads();                                  // all prologue DMA done

    // ---- Init windows (rows br = 8mg..8mg+7 <= 63) + filter queue ----
    float4 wE[M_], wO[M_], ae[M_], ao[M_];
#pragma unroll
    for (int m = 0; m < M_; ++m) {
        wE[m] = ldrow(8 * mg + 2 * m);
        wO[m] = ldrow(8 * mg + 2 * m + 1);
        ae[m] = zf4(); ao[m] = zf4();
    }
    float4 qF0 = ldsF(0), qF1 = ldsF(1);              // dist-2 LDS queue

    // ---- One step (tap filt[t]); t compile-time under unroll ----
    auto dostep = [&](int t) {
        const float4 fv = qF0;
        qF0 = qF1;
        qF1 = (t + 2 <= 40) ? ldsF(t + 2) : zf4();
        if (t <= 20) {
#pragma unroll
            for (int m = 0; m < M_; ++m) { fma4(ae[m], fv, wE[m]); fma4(ao[m], fv, wO[m]); }
        } else {
#pragma unroll
            for (int m = 0; m < M_; ++m) { fma4(ao[m], fv, wE[m]); fma4(ae[m], fv, wO[m]); }
        }
        if (t < 40) {
#pragma unroll
            for (int m = 0; m < M_ - 1; ++m) wE[m] = wE[m + 1];
            wE[M_ - 1] = ldrow(8 * mg + 2 * t + 8);
            if (t != 20) {                            // O holds at junction
#pragma unroll
                for (int m = 0; m < M_ - 1; ++m) wO[m] = wO[m + 1];
                wO[M_ - 1] = ldrow(8 * mg + 2 * t + 8 + ((t < 20) ? 1 : -1));
            }
        }
    };

    // ---- Phases p=0..4 (8 steps; phase 4 has 9 incl. reg-only t=40) ----
#pragma unroll
    for (int p = 0; p < 5; ++p) {
        if (p <= 3) {                                 // stage one phase ahead
            stageX(16 * (p + 5) + 2 * mg);            // x chunk p+5 (2 rows/wave)
            stageX(16 * (p + 5) + 2 * mg + 1);
            stageF(p + 2);                            // filt chunk p+2 (1 row/wave)
        }
#pragma unroll
        for (int t = 8 * p; t < ((p == 4) ? 41 : 8 * p + 8); ++t) dostep(t);
        if (p < 4) __syncthreads();                   // drain DMA + fence reuse
    }

    // ---- Store 2*M_ output rows (coalesced float4 across 64 lanes) ----
#pragma unroll
    for (int m = 0; m < M_; ++m) {
        if (!CHK || (m0 + m) < S_) {
            *(float4*)(ob + (size_t)(2 * (m0 + m))     * D_) = ae[m];
            *(float4*)(ob + (size_t)(2 * (m0 + m) + 1) * D_) = ao[m];
        }
    }
}

__global__ __launch_bounds__(512, 1) void fsmn_kernel(
    const float* __restrict__ x, const float* __restrict__ filt,
    float* __restrict__ out)
{
    __shared__ float lds[LDS_FLOATS];      // 152 KiB: filt ring 24KB + x ring 128KB

    const int lane = threadIdx.x;          // 0..63
    const int mg   = threadIdx.y;          // 0..7 : m-group (one wave each)

    // XCD-chunked swizzle: 2048 blocks = 8 XCDs x 256 (exactly bijective).
    const int bid  = blockIdx.x;
    const int xcd  = bid & 7;
    const int slot = bid >> 3;
    const int n    = xcd * 256 + slot;     // linear id, mb-fastest
    const int mb   = n & 31;               // 0..31 : m-block (32 m each)
    const int rest = n >> 5;
    const int dh   = rest & 1;             // d-half
    const int b    = rest >> 1;            // batch

    const int m0b = mb * 32;
    const int m0  = m0b + mg * M_;
    const int d   = (dh * 64 + lane) * 4;
    const float* xb = x + (size_t)b * T_ * D_ + d;
    const float* fb = filt + d;
    float*       ob = out + (size_t)b * T_ * D_ + d;
    const int R0  = 2 * m0b - 40;          // x row of block-row 0

    // Interior iff staged rows br=0..143 all valid and all stores valid:
    // R0 >= 0 -> mb >= 1;  R0+143 <= 1999 -> mb <= 29.
    // No early-return — all 512 threads reach every barrier.
    if (mb >= 1 && mb <= 29) fsmn_body<false>(lds, xb, fb, ob, m0, R0, lane, mg);
    else                     fsmn_body<true >(lds, xb, fb, ob, m0, R0, lane, mg);
}

extern "C" void kernel_launch(void* const* d_in, const int* in_sizes, int n_in,
                              void* d_out, int out_size, void* d_ws, size_t ws_size,
                              hipStream_t stream) {
    const float* x    = (const float*)d_in[0];
    const float* filt = (const float*)d_in[1];
    float*       out  = (float*)d_out;

    dim3 block(64, 8, 1);
    // 32 m-blocks (32 m each) x 2 d-halves x 32 batches = 2048 blocks.
    dim3 grid(2048, 1, 1);
    hipLaunchKernelGGL(fsmn_kernel, grid, block, 0, stream, x, filt, out);
}